// Round 2
// baseline (420.343 us; speedup 1.0000x reference)
//
#include <hip/hip_runtime.h>
#include <math.h>

#define N_NODES 50000
#define N_EDGES 1600000
#define D_IN 128
#define D_OUT 32
#define ALPHA 0.2f

// Monotone float<->int key (involution). Works with signed atomicMin/Max.
__device__ __forceinline__ int enc_f(float x) {
    int i = __float_as_int(x);
    return i >= 0 ? i : (i ^ 0x7fffffff);
}
__device__ __forceinline__ float dec_f(int k) {
    return __int_as_float(k >= 0 ? k : (k ^ 0x7fffffff));
}

// Kernel A: X_prime = X @ W  [N,32], s0 = Xp.a0, s1 = Xp.a1.
// 8 nodes per 256-thread block; 32 lanes per node (one per output dim).
// Also initializes the min/max atomic slots (stream-ordered before use).
__global__ __launch_bounds__(256) void k_xw(const float* __restrict__ X,
                                            const float* __restrict__ W,
                                            const float* __restrict__ a0,
                                            const float* __restrict__ a1,
                                            float* __restrict__ Xp,
                                            float* __restrict__ s0,
                                            float* __restrict__ s1,
                                            int* __restrict__ minmax) {
    __shared__ float Wl[D_IN * D_OUT]; // 16 KiB
    __shared__ float Xl[8 * D_IN];     // 4 KiB
    const int tid = threadIdx.x;
    if (blockIdx.x == 0 && tid == 0) {
        minmax[0] = 0x7fffffff; // running min key
        minmax[1] = 0x80000000; // running max key
    }
    for (int i = tid; i < D_IN * D_OUT; i += 256) Wl[i] = W[i];
    const int node0 = blockIdx.x * 8; // 50000/8 = 6250 blocks, no tail
    for (int i = tid; i < 8 * D_IN; i += 256) Xl[i] = X[(size_t)node0 * D_IN + i];
    __syncthreads();

    const int g = tid >> 5;   // node group within block
    const int t = tid & 31;   // output dim
    const int node = node0 + g;
    const float* xr = &Xl[g * D_IN];
    float acc = 0.f;
#pragma unroll
    for (int k = 0; k < D_IN; ++k) acc += xr[k] * Wl[k * D_OUT + t];
    Xp[(size_t)node * D_OUT + t] = acc;

    float v0 = acc * a0[t];
    float v1 = acc * a1[t];
#pragma unroll
    for (int m = 16; m >= 1; m >>= 1) {
        v0 += __shfl_xor(v0, m);
        v1 += __shfl_xor(v1, m);
    }
    if (t == 0) { s0[node] = v0; s1[node] = v1; }
}

// Kernel B: fused per-row histogram (int atomics) + global min/max of
// leakyrelu(s0[row]+s1[col]) over all edges.
__global__ __launch_bounds__(256) void k_hist_minmax(const int* __restrict__ row,
                                                     const int* __restrict__ col,
                                                     const float* __restrict__ s0,
                                                     const float* __restrict__ s1,
                                                     int* __restrict__ counts,
                                                     int* __restrict__ minmax) {
    const int tid = blockIdx.x * blockDim.x + threadIdx.x;
    const int stride = gridDim.x * blockDim.x;
    int kmin = 0x7fffffff, kmax = 0x80000000;
    for (int e = tid; e < N_EDGES; e += stride) {
        const int r = row[e];
        atomicAdd(&counts[r], 1);
        float a = s0[r] + s1[col[e]];
        a = a > 0.f ? a : ALPHA * a;
        int k = enc_f(a);
        kmin = min(kmin, k);
        kmax = max(kmax, k);
    }
#pragma unroll
    for (int m = 32; m >= 1; m >>= 1) {
        kmin = min(kmin, __shfl_xor(kmin, m));
        kmax = max(kmax, __shfl_xor(kmax, m));
    }
    __shared__ int smn[4], smx[4];
    const int wave = threadIdx.x >> 6;
    if ((threadIdx.x & 63) == 0) { smn[wave] = kmin; smx[wave] = kmax; }
    __syncthreads();
    if (threadIdx.x == 0) {
#pragma unroll
        for (int w = 1; w < 4; ++w) { kmin = min(kmin, smn[w]); kmax = max(kmax, smx[w]); }
        atomicMin(&minmax[0], kmin);
        atomicMax(&minmax[1], kmax);
    }
}

// Kernel C: single-block exclusive scan of counts -> offsets (50000 elems).
__global__ __launch_bounds__(1024) void k_scan(const int* __restrict__ counts,
                                               int* __restrict__ offsets) {
    __shared__ int part[1024];
    const int t = threadIdx.x;
    const int CH = (N_NODES + 1023) / 1024; // 49
    const int lo = t * CH;
    const int hi = min(lo + CH, N_NODES);
    int s = 0;
    for (int i = lo; i < hi; ++i) s += counts[i];
    part[t] = s;
    __syncthreads();
    // Hillis-Steele inclusive scan
    for (int d = 1; d < 1024; d <<= 1) {
        int v = (t >= d) ? part[t - d] : 0;
        __syncthreads();
        part[t] += v;
        __syncthreads();
    }
    int run = (t > 0) ? part[t - 1] : 0; // exclusive prefix for this chunk
    for (int i = lo; i < hi; ++i) { offsets[i] = run; run += counts[i]; }
}

// Kernel D: fill CSR. For each edge: w = exp(minmaxnorm(leakyrelu(att)));
// pos = offsets[row]++ (atomic); edges[pos] = {col, w}.
// After this kernel offsets[r] == segment END for row r.
__global__ __launch_bounds__(256) void k_fill(const int* __restrict__ row,
                                              const int* __restrict__ col,
                                              const float* __restrict__ s0,
                                              const float* __restrict__ s1,
                                              const int* __restrict__ minmax,
                                              int* __restrict__ offsets,
                                              int2* __restrict__ edges) {
    const int e = blockIdx.x * 256 + threadIdx.x;
    if (e >= N_EDGES) return;
    const int r = row[e];
    const int c = col[e];
    float a = s0[r] + s1[c];
    a = a > 0.f ? a : ALPHA * a;
    const float mn = dec_f(minmax[0]);
    const float mx = dec_f(minmax[1]);
    const float w = __expf((a - mn) / (mx - mn));
    const int pos = atomicAdd(&offsets[r], 1);
    edges[pos] = make_int2(c, __float_as_int(w));
}

// Kernel E: gather. 32 lanes per destination node walk the node's CSR
// segment, accumulate sum(w * Xp[col]) and sum(w), write out once.
__global__ __launch_bounds__(256) void k_gather(const int* __restrict__ counts,
                                                const int* __restrict__ offsets,
                                                const int2* __restrict__ edges,
                                                const float* __restrict__ Xp,
                                                float* __restrict__ out) {
    const int tid = threadIdx.x;
    const int node = blockIdx.x * 8 + (tid >> 5); // 6250 blocks, no tail
    const int d = tid & 31;
    const int cnt = counts[node];
    const int end = offsets[node];     // post-fill: end of segment
    const int start = end - cnt;
    float acc = 0.f;
    float wsum = 0.f;
    for (int i = start; i < end; ++i) {
        const int2 ed = edges[i];       // broadcast load (same addr all lanes)
        const float w = __int_as_float(ed.y);
        acc += w * Xp[(size_t)ed.x * D_OUT + d];
        wsum += w;
    }
    out[(size_t)node * D_OUT + d] = acc / wsum;
}

extern "C" void kernel_launch(void* const* d_in, const int* in_sizes, int n_in,
                              void* d_out, int out_size, void* d_ws, size_t ws_size,
                              hipStream_t stream) {
    const float* X  = (const float*)d_in[0];
    const float* W  = (const float*)d_in[1];
    const float* a0 = (const float*)d_in[2];
    const float* a1 = (const float*)d_in[3];
    const int* row  = (const int*)d_in[4];
    const int* col  = (const int*)d_in[5];
    float* out = (float*)d_out;

    // Workspace layout (4B units):
    // [minmax: 64][counts: 50048][offsets: 50048][s0: 50048][s1: 50048]
    // [Xp: 1.6M][edges: 1.6M int2]
    float* ws = (float*)d_ws;
    int*   minmax  = (int*)ws;
    int*   counts  = (int*)(ws + 64);
    int*   offsets = counts + 50048;
    float* s0 = (float*)(offsets + 50048);
    float* s1 = s0 + 50048;
    float* Xp = s1 + 50048;
    int2*  edges = (int2*)(Xp + (size_t)N_NODES * D_OUT);

    hipMemsetAsync(counts, 0, (size_t)N_NODES * sizeof(int), stream);

    k_xw<<<N_NODES / 8, 256, 0, stream>>>(X, W, a0, a1, Xp, s0, s1, minmax);
    k_hist_minmax<<<1024, 256, 0, stream>>>(row, col, s0, s1, counts, minmax);
    k_scan<<<1, 1024, 0, stream>>>(counts, offsets);
    k_fill<<<(N_EDGES + 255) / 256, 256, 0, stream>>>(row, col, s0, s1, minmax,
                                                      offsets, edges);
    k_gather<<<N_NODES / 8, 256, 0, stream>>>(counts, offsets, edges, Xp, out);
}